// Round 8
// baseline (576.289 us; speedup 1.0000x reference)
//
#include <hip/hip_runtime.h>

// MHA forward.  B=4 T=2048 DM=1024 H=16 DK=DV=64.
// Inputs: f32 (x, Wq, Wk, Wv per reference).  Output: f32 [B,T,1024].
// (R7 probe proved d_out is f32 — bf16 writes were the 7-round red herring.)
// Kernel 1: QKV projection, MFMA 16x16x32 bf16 (f32 loads -> RTNE bf16
//           staging).  Q,K -> ws bf16 [B,HC,T,64]; V -> ws bf16 [B,HC,64,T].
// Kernel 2: flash-style causal attention, MFMA QK^T + PV, f32 output.
// Head-chunked (HC) so bf16 scratch fits ws_size.

#define B_  4
#define T_  2048
#define DM_ 1024
#define H_  16
#define D_  64
#define DMO 1024   // out row stride = H_*D_

typedef unsigned short u16;
typedef u16   u16x8 __attribute__((ext_vector_type(8)));
typedef short s16x8 __attribute__((ext_vector_type(8)));
typedef float f32x4 __attribute__((ext_vector_type(4)));

__device__ __forceinline__ float bf2f(u16 v) {
    unsigned u = ((unsigned)v) << 16;
    return __builtin_bit_cast(float, u);
}
__device__ __forceinline__ u16 f2bf(float f) {  // round-to-nearest-even
    unsigned u = __builtin_bit_cast(unsigned, f);
    u += 0x7FFFu + ((u >> 16) & 1u);
    return (u16)(u >> 16);
}
__device__ __forceinline__ f32x4 mfma16(u16x8 a, u16x8 b, f32x4 c) {
    return __builtin_amdgcn_mfma_f32_16x16x32_bf16(
        __builtin_bit_cast(s16x8, a), __builtin_bit_cast(s16x8, b), c, 0, 0, 0);
}
// 8 consecutive f32 -> bf16x8
__device__ __forceinline__ u16x8 load8_f32_bf(const float* f) {
    f32x4 a = *(const f32x4*)f;
    f32x4 b = *(const f32x4*)(f + 4);
    u16x8 r;
    r[0] = f2bf(a[0]); r[1] = f2bf(a[1]); r[2] = f2bf(a[2]); r[3] = f2bf(a[3]);
    r[4] = f2bf(b[0]); r[5] = f2bf(b[1]); r[6] = f2bf(b[2]); r[7] = f2bf(b[3]);
    return r;
}

// ---------------------------------------------------------------------------
// Projection: grid (128 m-tiles, HC heads, 3 mats), block 256 (4 waves).
// ---------------------------------------------------------------------------
__global__ __launch_bounds__(256) void proj_kernel(
    const float* __restrict__ x,  const float* __restrict__ Wq,
    const float* __restrict__ Wk, const float* __restrict__ Wv,
    int h0, int HC,
    u16* __restrict__ Qc, u16* __restrict__ Kc, u16* __restrict__ Vtc)
{
    __shared__ u16 Xs[64][72];   // 144B rows: 16B-aligned, +4 bank rotation
    __shared__ u16 Wt[64][72];   // transposed W tile: Wt[n][d]

    const int mt  = blockIdx.x;
    const int hl  = blockIdx.y;
    const int h   = h0 + hl;
    const int mat = blockIdx.z;
    const float* W = (mat == 0) ? Wq : (mat == 1) ? Wk : Wv;

    const int tid  = threadIdx.x;
    const int wave = tid >> 6, lane = tid & 63;
    const int quad = lane >> 4, l16 = lane & 15;
    const int m0   = mt * 64;
    const int lr   = tid >> 3;   // 0..31
    const int lv   = tid & 7;    // 0..7

    f32x4 acc[4];
    #pragma unroll
    for (int i = 0; i < 4; i++) acc[i] = f32x4{0.f, 0.f, 0.f, 0.f};

    for (int kb = 0; kb < 16; kb++) {
        const int kbase = kb * 64;
        #pragma unroll
        for (int p = 0; p < 64; p += 32) {
            u16x8 xv = load8_f32_bf(x + (size_t)(m0 + lr + p) * DM_ + kbase + lv * 8);
            *(u16x8*)&Xs[lr + p][lv * 8] = xv;
            u16x8 wv = load8_f32_bf(W + ((size_t)h * DM_ + kbase + lr + p) * D_ + lv * 8);
            #pragma unroll
            for (int e = 0; e < 8; e++) Wt[lv * 8 + e][lr + p] = wv[e];
        }
        __syncthreads();
        #pragma unroll
        for (int ks = 0; ks < 2; ks++) {
            // A[m=l16][k=quad*8+j]  (m120-verified A layout)
            u16x8 a = *(const u16x8*)&Xs[wave * 16 + l16][ks * 32 + quad * 8];
            #pragma unroll
            for (int nt = 0; nt < 4; nt++) {
                // B[k][n=l16] = Wt[n][k]
                u16x8 b = *(const u16x8*)&Wt[nt * 16 + l16][ks * 32 + quad * 8];
                acc[nt] = mfma16(a, b, acc[nt]);
            }
        }
        __syncthreads();
    }

    // C/D: row = quad*4+reg, col = l16 (m89-verified)
    #pragma unroll
    for (int nt = 0; nt < 4; nt++) {
        #pragma unroll
        for (int r = 0; r < 4; r++) {
            int m  = m0 + wave * 16 + quad * 4 + r;
            int bb = m >> 11, t = m & (T_ - 1);
            int n  = nt * 16 + l16;
            u16 val = f2bf(acc[nt][r]);
            if (mat == 2) {
                Vtc[((size_t)(bb * HC + hl) * D_ + n) * T_ + t] = val;
            } else {
                u16* dst = (mat == 0) ? Qc : Kc;
                dst[((size_t)(bb * HC + hl) * T_ + t) * D_ + n] = val;
            }
        }
    }
}

// ---------------------------------------------------------------------------
// Flash attention: grid (32 q-tiles, HC heads, 4 batch), block 256.
// Wave w owns q rows [q0+16w, q0+16w+16).  f32 output.
// ---------------------------------------------------------------------------
__global__ __launch_bounds__(256) void attn_kernel(
    const u16* __restrict__ Qc, const u16* __restrict__ Kc,
    const u16* __restrict__ Vtc, int h0, int HC, float* __restrict__ out)
{
    __shared__ u16 Ks[64][72];
    __shared__ u16 Vs[64][72];       // Vs[v][s]
    __shared__ u16 Ps[4][16][72];    // per-wave P tile

    const int qt = blockIdx.x, hl = blockIdx.y, b = blockIdx.z;
    const int h = h0 + hl;
    const int tid = threadIdx.x, wave = tid >> 6, lane = tid & 63;
    const int quad = lane >> 4, l16 = lane & 15;
    const int q0 = qt * 64;

    const u16* Qbh = Qc + (size_t)(b * HC + hl) * T_ * D_;
    const u16* Kbh = Kc + (size_t)(b * HC + hl) * T_ * D_;
    const u16* Vbh = Vtc + (size_t)(b * HC + hl) * D_ * T_;

    // Q fragments, pre-scaled by dk^-0.5 = 1/8 (exact in bf16)
    u16x8 qf[2];
    {
        int qrow = q0 + wave * 16 + l16;
        #pragma unroll
        for (int ks = 0; ks < 2; ks++) {
            u16x8 qv = *(const u16x8*)(Qbh + (size_t)qrow * D_ + ks * 32 + quad * 8);
            #pragma unroll
            for (int e = 0; e < 8; e++) qv[e] = f2bf(bf2f(qv[e]) * 0.125f);
            qf[ks] = qv;
        }
    }

    f32x4 o[4];
    #pragma unroll
    for (int i = 0; i < 4; i++) o[i] = f32x4{0.f, 0.f, 0.f, 0.f};
    float mi[4], li[4];
    #pragma unroll
    for (int r = 0; r < 4; r++) { mi[r] = -1e30f; li[r] = 0.f; }

    const int lr = tid >> 3, lv = tid & 7;
    const int nst = qt + 1;

    for (int st = 0; st < nst; st++) {
        const int s0 = st * 64;
        __syncthreads();   // protect previous iteration's Ks/Vs/Ps reads
        #pragma unroll
        for (int p = 0; p < 64; p += 32) {
            u16x8 kv = *(const u16x8*)(Kbh + (size_t)(s0 + lr + p) * D_ + lv * 8);
            *(u16x8*)&Ks[lr + p][lv * 8] = kv;
            u16x8 vv = *(const u16x8*)(Vbh + (size_t)(lr + p) * T_ + s0 + lv * 8);
            *(u16x8*)&Vs[lr + p][lv * 8] = vv;
        }
        __syncthreads();

        // S = (Q/8) K^T : D[m=q][n=s], B[k=d][n=s] = Ks[s][d]
        f32x4 s[4];
        #pragma unroll
        for (int i = 0; i < 4; i++) s[i] = f32x4{0.f, 0.f, 0.f, 0.f};
        #pragma unroll
        for (int ks = 0; ks < 2; ks++) {
            #pragma unroll
            for (int nt = 0; nt < 4; nt++) {
                u16x8 bfr = *(const u16x8*)&Ks[nt * 16 + l16][ks * 32 + quad * 8];
                s[nt] = mfma16(qf[ks], bfr, s[nt]);
            }
        }

        // causal mask — only the diagonal tile
        if (st == nst - 1) {
            #pragma unroll
            for (int nt = 0; nt < 4; nt++) {
                int sc = s0 + nt * 16 + l16;
                #pragma unroll
                for (int r = 0; r < 4; r++) {
                    int qr = q0 + wave * 16 + quad * 4 + r;
                    if (sc > qr) s[nt][r] = -1e30f;
                }
            }
        }

        // online softmax per row (row = quad*4+r; cols over the quad's 16 lanes)
        #pragma unroll
        for (int r = 0; r < 4; r++) {
            float mx = s[0][r];
            #pragma unroll
            for (int nt = 1; nt < 4; nt++) mx = fmaxf(mx, s[nt][r]);
            #pragma unroll
            for (int off = 1; off < 16; off <<= 1)
                mx = fmaxf(mx, __shfl_xor(mx, off));
            float mn = fmaxf(mi[r], mx);
            float alpha = __expf(mi[r] - mn);
            float sum = 0.f;
            #pragma unroll
            for (int nt = 0; nt < 4; nt++) {
                float p = __expf(s[nt][r] - mn);
                s[nt][r] = p;
                sum += p;
            }
            #pragma unroll
            for (int off = 1; off < 16; off <<= 1)
                sum += __shfl_xor(sum, off);
            li[r] = li[r] * alpha + sum;
            mi[r] = mn;
            #pragma unroll
            for (int nt = 0; nt < 4; nt++) o[nt][r] *= alpha;
        }

        // P: C-layout -> LDS -> A-layout (per-wave region, m120-verified)
        #pragma unroll
        for (int nt = 0; nt < 4; nt++)
            #pragma unroll
            for (int r = 0; r < 4; r++)
                Ps[wave][quad * 4 + r][nt * 16 + l16] = f2bf(s[nt][r]);
        __syncthreads();

        // O += P V : A[m=l16][k=s], B[k=s][n=v] = Vs[v][s]
        #pragma unroll
        for (int ks = 0; ks < 2; ks++) {
            u16x8 a = *(const u16x8*)&Ps[wave][l16][ks * 32 + quad * 8];
            #pragma unroll
            for (int nt = 0; nt < 4; nt++) {
                u16x8 bv = *(const u16x8*)&Vs[nt * 16 + l16][ks * 32 + quad * 8];
                o[nt] = mfma16(a, bv, o[nt]);
            }
        }
    }

    // f32 output: out[b][qr][h*64 + col]
    #pragma unroll
    for (int nt = 0; nt < 4; nt++) {
        #pragma unroll
        for (int r = 0; r < 4; r++) {
            int qr = q0 + wave * 16 + quad * 4 + r;
            out[(size_t)(b * T_ + qr) * DMO + h * D_ + nt * 16 + l16] =
                o[nt][r] / li[r];
        }
    }
}

// ---------------------------------------------------------------------------
extern "C" void kernel_launch(void* const* d_in, const int* in_sizes, int n_in,
                              void* d_out, int out_size, void* d_ws, size_t ws_size,
                              hipStream_t stream) {
    // Resolve inputs by element count: x = 8.4M, W's = 1M each (dict order).
    int xi = 0, wi[3] = {1, 2, 3};
    {
        int k = 0, found = 0;
        for (int i = 0; i < n_in && i < 8; i++) {
            if (in_sizes[i] == B_ * T_ * DM_) { xi = i; found = 1; }
            else if (in_sizes[i] == H_ * DM_ * D_ && k < 3) wi[k++] = i;
        }
        if (!found || k != 3) { xi = 0; wi[0] = 1; wi[1] = 2; wi[2] = 3; }
    }
    const float* x  = (const float*)d_in[xi];
    const float* Wq = (const float*)d_in[wi[0]];
    const float* Wk = (const float*)d_in[wi[1]];
    const float* Wv = (const float*)d_in[wi[2]];
    float* out = (float*)d_out;

    // bf16 scratch per head: Q+K+Vt = 3 MB.  Chunk heads to fit ws_size.
    const size_t perHead = (size_t)B_ * T_ * D_;   // elements (1 MB bf16)
    int HC = 16;
    while (HC > 1 && (size_t)HC * perHead * 3 * sizeof(u16) > ws_size) HC >>= 1;

    u16* Qc  = (u16*)d_ws;
    u16* Kc  = Qc + perHead * HC;
    u16* Vtc = Kc + perHead * HC;

    for (int h0 = 0; h0 < H_; h0 += HC) {
        proj_kernel<<<dim3(128, HC, 3), 256, 0, stream>>>(x, Wq, Wk, Wv, h0, HC,
                                                          Qc, Kc, Vtc);
        attn_kernel<<<dim3(32, HC, 4), 256, 0, stream>>>(Qc, Kc, Vtc, h0, HC, out);
    }
}

// Round 9
// 540.973 us; speedup vs baseline: 1.0653x; 1.0653x over previous
//
#include <hip/hip_runtime.h>

// MHA forward.  B=4 T=2048 DM=1024 H=16 DK=DV=64.  f32 in / f32 out.
// R9: proj = ONE combined GEMM [8192x1024]@[1024x3072] (Q|K|V, all heads),
//     128x128 tiles, bank-conflict-free transpose staging (rotated slots;
//     R8 counter showed 1.04e8 conflict-cycles from the naive scatter).
//     attn = flash, 128-row q-tiles, P C->A via wave-private LDS with NO
//     barrier (intra-wave DS ordering), 2 barriers per 64-col s-tile.

#define B_  4
#define T_  2048
#define DM_ 1024
#define H_  16
#define D_  64
#define DMO 1024   // out row stride = H_*D_

typedef unsigned short u16;
typedef u16   u16x8 __attribute__((ext_vector_type(8)));
typedef short s16x8 __attribute__((ext_vector_type(8)));
typedef float f32x4 __attribute__((ext_vector_type(4)));

__device__ __forceinline__ float bf2f(u16 v) {
    unsigned u = ((unsigned)v) << 16;
    return __builtin_bit_cast(float, u);
}
__device__ __forceinline__ u16 f2bf(float f) {  // round-to-nearest-even
    unsigned u = __builtin_bit_cast(unsigned, f);
    u += 0x7FFFu + ((u >> 16) & 1u);
    return (u16)(u >> 16);
}
__device__ __forceinline__ f32x4 mfma16(u16x8 a, u16x8 b, f32x4 c) {
    return __builtin_amdgcn_mfma_f32_16x16x32_bf16(
        __builtin_bit_cast(s16x8, a), __builtin_bit_cast(s16x8, b), c, 0, 0, 0);
}

// ---------------------------------------------------------------------------
// Projection GEMM: C[8192][3072] = X[8192][1024] @ [Wq|Wk|Wv] (heads concat).
// grid (64 m-tiles, 24 n-tiles), block 256 = 4 waves in 2x2 (each 64x64).
// Outputs bf16: Q,K -> [B,H,T,64]; V -> transposed [B,H,64,T].
// ---------------------------------------------------------------------------
__global__ __launch_bounds__(256) void proj_kernel(
    const float* __restrict__ x,  const float* __restrict__ Wq,
    const float* __restrict__ Wk, const float* __restrict__ Wv,
    u16* __restrict__ Qc, u16* __restrict__ Kc, u16* __restrict__ Vtc)
{
    __shared__ u16 As[128][72];   // As[m][k]
    __shared__ u16 Bs[128][72];   // Bs[n][k]  (n local 0..127 = 2 heads x 64)

    const int m0  = blockIdx.x * 128;
    const int n0  = blockIdx.y * 128;            // combined col: mat*1024 + h*64 + dk
    const int mat = n0 >> 10;
    const float* W = (mat == 0) ? Wq : (mat == 1) ? Wk : Wv;
    const int hA  = (n0 & 1023) >> 6;            // heads hA, hA+1

    const int tid  = threadIdx.x;
    const int wave = tid >> 6, lane = tid & 63;
    const int quad = lane >> 4, l16 = lane & 15;
    const int wm   = wave >> 1, wn = wave & 1;

    // X staging: row = p*64 + (tid>>2), 16 f32 at col (tid&3)*16
    const int xr = tid >> 2, xc = (tid & 3) * 16;

    f32x4 acc[4][4];
    #pragma unroll
    for (int i = 0; i < 4; i++)
        #pragma unroll
        for (int j = 0; j < 4; j++) acc[i][j] = f32x4{0.f, 0.f, 0.f, 0.f};

    for (int kb = 0; kb < 16; kb++) {
        const int kbase = kb * 64;
        __syncthreads();
        // --- stage X tile (128 x 64) ---
        #pragma unroll
        for (int p = 0; p < 2; p++) {
            const int row = p * 64 + xr;
            const float* src = x + (size_t)(m0 + row) * DM_ + kbase + xc;
            #pragma unroll
            for (int g = 0; g < 2; g++) {
                f32x4 a = *(const f32x4*)(src + g * 8);
                f32x4 b = *(const f32x4*)(src + g * 8 + 4);
                u16x8 v;
                v[0]=f2bf(a[0]); v[1]=f2bf(a[1]); v[2]=f2bf(a[2]); v[3]=f2bf(a[3]);
                v[4]=f2bf(b[0]); v[5]=f2bf(b[1]); v[6]=f2bf(b[2]); v[7]=f2bf(b[3]);
                *(u16x8*)&As[row][xc + g * 8] = v;
            }
        }
        // --- stage W tile transposed: Bs[n][k] = W[hA + n/64][kbase+k][n%64] ---
        #pragma unroll
        for (int pp = 0; pp < 4; pp++) {
            const int task = pp * 256 + tid;
            const int hh  = task >> 9;           // 0/1
            const int d   = (task >> 3) & 63;    // k within tile
            const int dkg = task & 7;            // dk group of 8
            const float* src = W + ((size_t)(hA + hh) * DM_ + kbase + d) * D_ + dkg * 8;
            f32x4 a = *(const f32x4*)src;
            f32x4 b = *(const f32x4*)(src + 4);
            u16 v[8];
            v[0]=f2bf(a[0]); v[1]=f2bf(a[1]); v[2]=f2bf(a[2]); v[3]=f2bf(a[3]);
            v[4]=f2bf(b[0]); v[5]=f2bf(b[1]); v[6]=f2bf(b[2]); v[7]=f2bf(b[3]);
            const int bn = hh * 64 + dkg * 8;
            // rotated slot order: lane's 8 scatter writes hit distinct banks
            // across the wave each slot (naive order = 16-way conflict, R8 PMC)
            #pragma unroll
            for (int e = 0; e < 8; e++) {
                const int ee = (e + dkg) & 7;
                Bs[bn + ee][d] = v[ee];
            }
        }
        __syncthreads();

        // --- MFMA: each wave 64x64 quadrant, 4x4 frags, k=64 ---
        #pragma unroll
        for (int ks = 0; ks < 2; ks++) {
            u16x8 af[4], bf[4];
            #pragma unroll
            for (int i = 0; i < 4; i++)
                af[i] = *(const u16x8*)&As[wm * 64 + i * 16 + l16][ks * 32 + quad * 8];
            #pragma unroll
            for (int j = 0; j < 4; j++)
                bf[j] = *(const u16x8*)&Bs[wn * 64 + j * 16 + l16][ks * 32 + quad * 8];
            #pragma unroll
            for (int i = 0; i < 4; i++)
                #pragma unroll
                for (int j = 0; j < 4; j++)
                    acc[i][j] = mfma16(af[i], bf[j], acc[i][j]);
        }
    }

    // --- epilogue: C/D row = quad*4+r, col = l16 (m89) ---
    #pragma unroll
    for (int i = 0; i < 4; i++) {
        #pragma unroll
        for (int j = 0; j < 4; j++) {
            #pragma unroll
            for (int r = 0; r < 4; r++) {
                const int m  = m0 + wm * 64 + i * 16 + quad * 4 + r;
                const int bb = m >> 11, t = m & (T_ - 1);
                const int nloc = wn * 64 + j * 16 + l16;
                const int h  = hA + (nloc >> 6);
                const int dk = nloc & 63;
                const u16 val = f2bf(acc[i][j][r]);
                if (mat == 2) {
                    Vtc[((size_t)(bb * H_ + h) * D_ + dk) * T_ + t] = val;
                } else {
                    u16* dst = (mat == 0) ? Qc : Kc;
                    dst[((size_t)(bb * H_ + h) * T_ + t) * D_ + dk] = val;
                }
            }
        }
    }
}

// ---------------------------------------------------------------------------
// Flash attention: grid (16 q-tiles of 128, 16 heads, 4 batch), block 256.
// Wave w owns q rows [q0+32w, q0+32w+32) as two 16-row m-frags.
// ---------------------------------------------------------------------------
__global__ __launch_bounds__(256) void attn_kernel(
    const u16* __restrict__ Qc, const u16* __restrict__ Kc,
    const u16* __restrict__ Vtc, float* __restrict__ out)
{
    __shared__ u16 Ks[64][72];
    __shared__ u16 Vs[64][72];       // Vs[v][s]
    __shared__ u16 Ps[4][32][72];    // per-wave P tile (32 q-rows x 64 s)

    const int qt = blockIdx.x, h = blockIdx.y, b = blockIdx.z;
    const int tid = threadIdx.x, wave = tid >> 6, lane = tid & 63;
    const int quad = lane >> 4, l16 = lane & 15;
    const int q0 = qt * 128;

    const u16* Qbh = Qc + (size_t)(b * H_ + h) * T_ * D_;
    const u16* Kbh = Kc + (size_t)(b * H_ + h) * T_ * D_;
    const u16* Vbh = Vtc + (size_t)(b * H_ + h) * D_ * T_;

    // Q fragments (2 m-frags), pre-scaled by dk^-0.5 = 1/8
    u16x8 qf[2][2];
    #pragma unroll
    for (int mf = 0; mf < 2; mf++) {
        const int qrow = q0 + wave * 32 + mf * 16 + l16;
        #pragma unroll
        for (int ks = 0; ks < 2; ks++) {
            u16x8 qv = *(const u16x8*)(Qbh + (size_t)qrow * D_ + ks * 32 + quad * 8);
            #pragma unroll
            for (int e = 0; e < 8; e++) qv[e] = f2bf(bf2f(qv[e]) * 0.125f);
            qf[mf][ks] = qv;
        }
    }

    f32x4 o[2][4];
    float mi[2][4], li[2][4];
    #pragma unroll
    for (int mf = 0; mf < 2; mf++)
        #pragma unroll
        for (int i = 0; i < 4; i++) {
            o[mf][i] = f32x4{0.f, 0.f, 0.f, 0.f};
            mi[mf][i] = -1e30f; li[mf][i] = 0.f;
        }

    const int lr = tid >> 3, lv = tid & 7;
    const int nst = 2 * qt + 2;

    for (int st = 0; st < nst; st++) {
        const int s0 = st * 64;
        __syncthreads();   // prev-iter Ks/Vs readers done
        #pragma unroll
        for (int p = 0; p < 64; p += 32) {
            u16x8 kv = *(const u16x8*)(Kbh + (size_t)(s0 + lr + p) * D_ + lv * 8);
            *(u16x8*)&Ks[lr + p][lv * 8] = kv;
            u16x8 vv = *(const u16x8*)(Vbh + (size_t)(lr + p) * T_ + s0 + lv * 8);
            *(u16x8*)&Vs[lr + p][lv * 8] = vv;
        }
        __syncthreads();

        // S = (Q/8) K^T
        f32x4 s[2][4];
        #pragma unroll
        for (int mf = 0; mf < 2; mf++)
            #pragma unroll
            for (int i = 0; i < 4; i++) s[mf][i] = f32x4{0.f, 0.f, 0.f, 0.f};
        #pragma unroll
        for (int ks = 0; ks < 2; ks++) {
            u16x8 bfr[4];
            #pragma unroll
            for (int nt = 0; nt < 4; nt++)
                bfr[nt] = *(const u16x8*)&Ks[nt * 16 + l16][ks * 32 + quad * 8];
            #pragma unroll
            for (int mf = 0; mf < 2; mf++)
                #pragma unroll
                for (int nt = 0; nt < 4; nt++)
                    s[mf][nt] = mfma16(qf[mf][ks], bfr[nt], s[mf][nt]);
        }

        // causal mask — last two tiles only
        if (st >= nst - 2) {
            #pragma unroll
            for (int mf = 0; mf < 2; mf++)
                #pragma unroll
                for (int nt = 0; nt < 4; nt++) {
                    const int sc = s0 + nt * 16 + l16;
                    #pragma unroll
                    for (int r = 0; r < 4; r++) {
                        const int qr = q0 + wave * 32 + mf * 16 + quad * 4 + r;
                        if (sc > qr) s[mf][nt][r] = -1e30f;
                    }
                }
        }

        // online softmax per row (8 rows/wave; cols over the quad's 16 lanes)
        #pragma unroll
        for (int mf = 0; mf < 2; mf++) {
            #pragma unroll
            for (int r = 0; r < 4; r++) {
                float mx = s[mf][0][r];
                #pragma unroll
                for (int nt = 1; nt < 4; nt++) mx = fmaxf(mx, s[mf][nt][r]);
                #pragma unroll
                for (int off = 1; off < 16; off <<= 1)
                    mx = fmaxf(mx, __shfl_xor(mx, off));
                const float mn = fmaxf(mi[mf][r], mx);
                const float alpha = __expf(mi[mf][r] - mn);
                float sum = 0.f;
                #pragma unroll
                for (int nt = 0; nt < 4; nt++) {
                    const float p = __expf(s[mf][nt][r] - mn);
                    s[mf][nt][r] = p;
                    sum += p;
                }
                #pragma unroll
                for (int off = 1; off < 16; off <<= 1)
                    sum += __shfl_xor(sum, off);
                li[mf][r] = li[mf][r] * alpha + sum;
                mi[mf][r] = mn;
                #pragma unroll
                for (int nt = 0; nt < 4; nt++) o[mf][nt][r] *= alpha;
            }
        }

        // P: C-layout -> wave-private LDS -> A-layout.  NO barrier needed:
        // DS ops within a wave execute in order; region is wave-private.
        #pragma unroll
        for (int mf = 0; mf < 2; mf++)
            #pragma unroll
            for (int nt = 0; nt < 4; nt++)
                #pragma unroll
                for (int r = 0; r < 4; r++)
                    Ps[wave][mf * 16 + quad * 4 + r][nt * 16 + l16] = f2bf(s[mf][nt][r]);

        // O += P V : A[m=l16][k=s], B[k=s][n=v] = Vs[v][s]
        #pragma unroll
        for (int ks = 0; ks < 2; ks++) {
            u16x8 bv[4];
            #pragma unroll
            for (int nt = 0; nt < 4; nt++)
                bv[nt] = *(const u16x8*)&Vs[nt * 16 + l16][ks * 32 + quad * 8];
            #pragma unroll
            for (int mf = 0; mf < 2; mf++) {
                u16x8 a = *(const u16x8*)&Ps[wave][mf * 16 + l16][ks * 32 + quad * 8];
                #pragma unroll
                for (int nt = 0; nt < 4; nt++)
                    o[mf][nt] = mfma16(a, bv[nt], o[mf][nt]);
            }
        }
    }

    // f32 output
    #pragma unroll
    for (int mf = 0; mf < 2; mf++)
        #pragma unroll
        for (int nt = 0; nt < 4; nt++)
            #pragma unroll
            for (int r = 0; r < 4; r++) {
                const int qr = q0 + wave * 32 + mf * 16 + quad * 4 + r;
                out[(size_t)(b * T_ + qr) * DMO + h * D_ + nt * 16 + l16] =
                    o[mf][nt][r] / li[mf][r];
            }
}

// ---------------------------------------------------------------------------
extern "C" void kernel_launch(void* const* d_in, const int* in_sizes, int n_in,
                              void* d_out, int out_size, void* d_ws, size_t ws_size,
                              hipStream_t stream) {
    int xi = 0, wi[3] = {1, 2, 3};
    {
        int k = 0, found = 0;
        for (int i = 0; i < n_in && i < 8; i++) {
            if (in_sizes[i] == B_ * T_ * DM_) { xi = i; found = 1; }
            else if (in_sizes[i] == H_ * DM_ * D_ && k < 3) wi[k++] = i;
        }
        if (!found || k != 3) { xi = 0; wi[0] = 1; wi[1] = 2; wi[2] = 3; }
    }
    const float* x  = (const float*)d_in[xi];
    const float* Wq = (const float*)d_in[wi[0]];
    const float* Wk = (const float*)d_in[wi[1]];
    const float* Wv = (const float*)d_in[wi[2]];
    float* out = (float*)d_out;

    // bf16 scratch: Q + K + Vt = 3 x 16.8 MB (R8 ran un-chunked => ws fits)
    const size_t per = (size_t)B_ * H_ * T_ * D_;
    u16* Qc  = (u16*)d_ws;
    u16* Kc  = Qc + per;
    u16* Vtc = Kc + per;

    proj_kernel<<<dim3(64, 24), 256, 0, stream>>>(x, Wq, Wk, Wv, Qc, Kc, Vtc);
    attn_kernel<<<dim3(16, 16, 4), 256, 0, stream>>>(Qc, Kc, Vtc, out);
}

// Round 10
// 298.887 us; speedup vs baseline: 1.9281x; 1.8100x over previous
//
#include <hip/hip_runtime.h>

// MHA forward.  B=4 T=2048 DM=1024 H=16 DK=DV=64.  f32 in / f32 out.
// R10: convert-once (xb bf16, Wt bf16 transposed — both scratch in d_out,
//      dead before attn writes it), m93-style bf16 B^T proj GEMM (128x128,
//      straight u16x8 staging, no transposes in hot loop), attn with
//      paired q-tiles (qt, 15-qt) for perfect per-CU balance + cheap
//      half-up bf16 packing (+0x8000, v_perm) + Q pre-scaled at proj.

#define B_  4
#define T_  2048
#define DM_ 1024
#define H_  16
#define D_  64
#define DMO 1024   // out row stride = H_*D_

typedef unsigned short u16;
typedef unsigned int   u32;
typedef u16   u16x8 __attribute__((ext_vector_type(8)));
typedef short s16x8 __attribute__((ext_vector_type(8)));
typedef float f32x4 __attribute__((ext_vector_type(4)));
typedef u32   u32x4 __attribute__((ext_vector_type(4)));

__device__ __forceinline__ u16 f2bf_hu(float f) {   // round-half-up (ties rare)
    u32 u = __builtin_bit_cast(u32, f) + 0x8000u;
    return (u16)(u >> 16);
}
// pack two f32 -> dword of two bf16 (lo,hi), 3 VALU ops
__device__ __forceinline__ u32 pk2(float lo, float hi) {
    u32 ul = __builtin_bit_cast(u32, lo) + 0x8000u;
    u32 uh = __builtin_bit_cast(u32, hi) + 0x8000u;
    return __builtin_amdgcn_perm(uh, ul, 0x07060302);  // [uh.hi16 : ul.hi16]
}
__device__ __forceinline__ u16x8 cvt8(const float* s) {
    f32x4 a = *(const f32x4*)s;
    f32x4 b = *(const f32x4*)(s + 4);
    u32x4 r { pk2(a[0], a[1]), pk2(a[2], a[3]), pk2(b[0], b[1]), pk2(b[2], b[3]) };
    return __builtin_bit_cast(u16x8, r);
}
__device__ __forceinline__ f32x4 mfma16(u16x8 a, u16x8 b, f32x4 c) {
    return __builtin_amdgcn_mfma_f32_16x16x32_bf16(
        __builtin_bit_cast(s16x8, a), __builtin_bit_cast(s16x8, b), c, 0, 0, 0);
}

// ---------------------------------------------------------------------------
// cvt_x: x f32 [8192][1024] -> xb bf16 (same layout).  1024 blocks x 256.
// ---------------------------------------------------------------------------
__global__ __launch_bounds__(256) void cvt_x(const float* __restrict__ x,
                                             u16* __restrict__ xb) {
    size_t i0 = ((size_t)blockIdx.x * 256 + threadIdx.x) * 32;
    #pragma unroll
    for (int c = 0; c < 4; c++)
        *(u16x8*)(xb + i0 + c * 8) = cvt8(x + i0 + c * 8);
}

// ---------------------------------------------------------------------------
// cvt_w: W[mat][h][d=1024][dk=64] f32 -> Wt[(mat*16+h)*64+dk][d=1024] bf16.
// grid (16 d-blocks, 16 h, 3 mat), 256 threads; LDS transpose.
// ---------------------------------------------------------------------------
__global__ __launch_bounds__(256) void cvt_w(
    const float* __restrict__ Wq, const float* __restrict__ Wk,
    const float* __restrict__ Wv, u16* __restrict__ Wt) {
    __shared__ u16 L[64][74];
    const int dblk = blockIdx.x, h = blockIdx.y, mat = blockIdx.z;
    const float* W = (mat == 0) ? Wq : (mat == 1) ? Wk : Wv;
    const int tid = threadIdx.x;
    {   // load 64(d) x 64(dk), coalesced, convert
        const int dl = tid >> 2, c = (tid & 3) * 16;
        const float* src = W + ((size_t)h * DM_ + dblk * 64 + dl) * D_ + c;
        #pragma unroll
        for (int g = 0; g < 2; g++)
            *(u16x8*)&L[dl][c + g * 8] = cvt8(src + g * 8);
    }
    __syncthreads();
    {   // write rows of Wt: row = dk, 16 d's per thread
        const int dkr = tid >> 2, g = tid & 3;
        u16 tmp[16];
        #pragma unroll
        for (int j = 0; j < 16; j++) tmp[j] = L[g * 16 + j][dkr];
        u16* dst = Wt + ((size_t)(mat * 16 + h) * 64 + dkr) * DM_ + dblk * 64 + g * 16;
        *(u16x8*)dst = *(u16x8*)tmp;
        *(u16x8*)(dst + 8) = *(u16x8*)(tmp + 8);
    }
}

// ---------------------------------------------------------------------------
// Projection GEMM: C[8192][3072] = xb @ Wt^T (Wt rows are C-columns).
// grid (64 m-tiles, 24 n-tiles), 256 thr = 4 waves 2x2, 128x128 tile, BK=64.
// Q (pre-scaled by 1/8), K -> [B,H,T,64]; V -> transposed [B,H,64,T].
// ---------------------------------------------------------------------------
__global__ __launch_bounds__(256) void proj_kernel(
    const u16* __restrict__ xb, const u16* __restrict__ Wt,
    u16* __restrict__ Qc, u16* __restrict__ Kc, u16* __restrict__ Vtc)
{
    __shared__ u16 As[128][72];   // [m][k]
    __shared__ u16 Bs[128][72];   // [n][k]

    const int m0 = blockIdx.x * 128;
    const int n0 = blockIdx.y * 128;          // n = mat*1024 + h*64 + dk
    const int mat = n0 >> 10;
    const int tid  = threadIdx.x;
    const int wave = tid >> 6, lane = tid & 63;
    const int quad = lane >> 4, l16 = lane & 15;
    const int wm   = wave >> 1, wn = wave & 1;

    f32x4 acc[4][4];
    #pragma unroll
    for (int i = 0; i < 4; i++)
        #pragma unroll
        for (int j = 0; j < 4; j++) acc[i][j] = f32x4{0.f, 0.f, 0.f, 0.f};

    for (int kb = 0; kb < 16; kb++) {
        const int kbase = kb * 64;
        __syncthreads();
        #pragma unroll
        for (int l = 0; l < 4; l++) {
            const int c   = l * 256 + tid;       // 0..1023 chunk id
            const int row = c >> 3, kc = (c & 7) * 8;
            *(u16x8*)&As[row][kc] =
                *(const u16x8*)(xb + (size_t)(m0 + row) * DM_ + kbase + kc);
            *(u16x8*)&Bs[row][kc] =
                *(const u16x8*)(Wt + (size_t)(n0 + row) * DM_ + kbase + kc);
        }
        __syncthreads();
        #pragma unroll
        for (int ks = 0; ks < 2; ks++) {
            u16x8 af[4], bf[4];
            #pragma unroll
            for (int i = 0; i < 4; i++)
                af[i] = *(const u16x8*)&As[wm * 64 + i * 16 + l16][ks * 32 + quad * 8];
            #pragma unroll
            for (int j = 0; j < 4; j++)
                bf[j] = *(const u16x8*)&Bs[wn * 64 + j * 16 + l16][ks * 32 + quad * 8];
            #pragma unroll
            for (int i = 0; i < 4; i++)
                #pragma unroll
                for (int j = 0; j < 4; j++)
                    acc[i][j] = mfma16(af[i], bf[j], acc[i][j]);
        }
    }

    // epilogue: C/D row = quad*4+r, col = l16 (m89)
    #pragma unroll
    for (int i = 0; i < 4; i++) {
        #pragma unroll
        for (int j = 0; j < 4; j++) {
            #pragma unroll
            for (int r = 0; r < 4; r++) {
                const int m  = m0 + wm * 64 + i * 16 + quad * 4 + r;
                const int bb = m >> 11, t = m & (T_ - 1);
                const int nloc = wn * 64 + j * 16 + l16;
                const int h  = ((n0 & 1023) >> 6) + (nloc >> 6);
                const int dk = nloc & 63;
                float v = acc[i][j][r];
                if (mat == 0) {        // Q pre-scaled by dk^-0.5 = 1/8
                    Qc[((size_t)(bb * H_ + h) * T_ + t) * D_ + dk] = f2bf_hu(v * 0.125f);
                } else if (mat == 1) {
                    Kc[((size_t)(bb * H_ + h) * T_ + t) * D_ + dk] = f2bf_hu(v);
                } else {
                    Vtc[((size_t)(bb * H_ + h) * D_ + dk) * T_ + t] = f2bf_hu(v);
                }
            }
        }
    }
}

// ---------------------------------------------------------------------------
// Flash attention, paired q-tiles: grid (8 pairs, 16 heads, 4 batch) x 256.
// Block handles q-tiles {bx, 15-bx} (128 rows each) -> every block does
// exactly 34 s-tiles => perfect per-CU balance (R9: 12.9% occupancy from
// linear qt->CU imbalance).  Wave owns 32 q-rows as two 16-row m-frags.
// ---------------------------------------------------------------------------
__global__ __launch_bounds__(256) void attn_kernel(
    const u16* __restrict__ Qc, const u16* __restrict__ Kc,
    const u16* __restrict__ Vtc, float* __restrict__ out)
{
    __shared__ u16 Ks[64][72];
    __shared__ u16 Vs[64][72];       // Vs[v][s]
    __shared__ u16 Ps[4][32][72];    // per-wave P tile

    const int h = blockIdx.y, b = blockIdx.z;
    const int tid = threadIdx.x, wave = tid >> 6, lane = tid & 63;
    const int quad = lane >> 4, l16 = lane & 15;

    const u16* Qbh = Qc + (size_t)(b * H_ + h) * T_ * D_;
    const u16* Kbh = Kc + (size_t)(b * H_ + h) * T_ * D_;
    const u16* Vbh = Vtc + (size_t)(b * H_ + h) * D_ * T_;
    const int lr = tid >> 3, lv = tid & 7;

    for (int ph = 0; ph < 2; ph++) {
        const int qt = ph ? (15 - blockIdx.x) : blockIdx.x;
        const int q0 = qt * 128;

        // Q fragments (already scaled by 1/8 at projection)
        u16x8 qf[2][2];
        #pragma unroll
        for (int mf = 0; mf < 2; mf++) {
            const int qrow = q0 + wave * 32 + mf * 16 + l16;
            #pragma unroll
            for (int ks = 0; ks < 2; ks++)
                qf[mf][ks] = *(const u16x8*)(Qbh + (size_t)qrow * D_ + ks * 32 + quad * 8);
        }

        f32x4 o[2][4];
        float mi[2][4], li[2][4];
        #pragma unroll
        for (int mf = 0; mf < 2; mf++)
            #pragma unroll
            for (int i = 0; i < 4; i++) {
                o[mf][i] = f32x4{0.f, 0.f, 0.f, 0.f};
                mi[mf][i] = -1e30f; li[mf][i] = 0.f;
            }

        const int nst = 2 * qt + 2;
        for (int st = 0; st < nst; st++) {
            const int s0 = st * 64;
            __syncthreads();
            #pragma unroll
            for (int p = 0; p < 64; p += 32) {
                *(u16x8*)&Ks[lr + p][lv * 8] =
                    *(const u16x8*)(Kbh + (size_t)(s0 + lr + p) * D_ + lv * 8);
                *(u16x8*)&Vs[lr + p][lv * 8] =
                    *(const u16x8*)(Vbh + (size_t)(lr + p) * T_ + s0 + lv * 8);
            }
            __syncthreads();

            // S = Q K^T
            f32x4 s[2][4];
            #pragma unroll
            for (int mf = 0; mf < 2; mf++)
                #pragma unroll
                for (int i = 0; i < 4; i++) s[mf][i] = f32x4{0.f, 0.f, 0.f, 0.f};
            #pragma unroll
            for (int ks = 0; ks < 2; ks++) {
                u16x8 bfr[4];
                #pragma unroll
                for (int nt = 0; nt < 4; nt++)
                    bfr[nt] = *(const u16x8*)&Ks[nt * 16 + l16][ks * 32 + quad * 8];
                #pragma unroll
                for (int mf = 0; mf < 2; mf++)
                    #pragma unroll
                    for (int nt = 0; nt < 4; nt++)
                        s[mf][nt] = mfma16(qf[mf][ks], bfr[nt], s[mf][nt]);
            }

            // causal mask — last two s-tiles of this q-tile only
            if (st >= nst - 2) {
                #pragma unroll
                for (int mf = 0; mf < 2; mf++)
                    #pragma unroll
                    for (int nt = 0; nt < 4; nt++) {
                        const int sc = s0 + nt * 16 + l16;
                        #pragma unroll
                        for (int r = 0; r < 4; r++) {
                            const int qr = q0 + wave * 32 + mf * 16 + quad * 4 + r;
                            if (sc > qr) s[mf][nt][r] = -1e30f;
                        }
                    }
            }

            // online softmax (row = quad*4+r; cols over quad's 16 lanes)
            #pragma unroll
            for (int mf = 0; mf < 2; mf++) {
                #pragma unroll
                for (int r = 0; r < 4; r++) {
                    float mx = fmaxf(fmaxf(s[mf][0][r], s[mf][1][r]),
                                     fmaxf(s[mf][2][r], s[mf][3][r]));
                    #pragma unroll
                    for (int off = 1; off < 16; off <<= 1)
                        mx = fmaxf(mx, __shfl_xor(mx, off));
                    const float mn = fmaxf(mi[mf][r], mx);
                    const float alpha = __expf(mi[mf][r] - mn);
                    float sum = 0.f;
                    #pragma unroll
                    for (int nt = 0; nt < 4; nt++) {
                        const float p = __expf(s[mf][nt][r] - mn);
                        s[mf][nt][r] = p;
                        sum += p;
                    }
                    #pragma unroll
                    for (int off = 1; off < 16; off <<= 1)
                        sum += __shfl_xor(sum, off);
                    li[mf][r] = li[mf][r] * alpha + sum;
                    mi[mf][r] = mn;
                    #pragma unroll
                    for (int nt = 0; nt < 4; nt++) o[mf][nt][r] *= alpha;
                }
            }

            // P: C-layout -> wave-private LDS (no barrier: intra-wave DS order)
            #pragma unroll
            for (int mf = 0; mf < 2; mf++)
                #pragma unroll
                for (int nt = 0; nt < 4; nt++)
                    #pragma unroll
                    for (int r = 0; r < 4; r++)
                        Ps[wave][mf * 16 + quad * 4 + r][nt * 16 + l16] =
                            f2bf_hu(s[mf][nt][r]);

            // O += P V
            #pragma unroll
            for (int ks = 0; ks < 2; ks++) {
                u16x8 bv[4];
                #pragma unroll
                for (int nt = 0; nt < 4; nt++)
                    bv[nt] = *(const u16x8*)&Vs[nt * 16 + l16][ks * 32 + quad * 8];
                #pragma unroll
                for (int mf = 0; mf < 2; mf++) {
                    u16x8 a = *(const u16x8*)&Ps[wave][mf * 16 + l16][ks * 32 + quad * 8];
                    #pragma unroll
                    for (int nt = 0; nt < 4; nt++)
                        o[mf][nt] = mfma16(a, bv[nt], o[mf][nt]);
                }
            }
        }

        // f32 output
        #pragma unroll
        for (int mf = 0; mf < 2; mf++)
            #pragma unroll
            for (int nt = 0; nt < 4; nt++)
                #pragma unroll
                for (int r = 0; r < 4; r++) {
                    const int qr = q0 + wave * 32 + mf * 16 + quad * 4 + r;
                    out[(size_t)(b * T_ + qr) * DMO + h * D_ + nt * 16 + l16] =
                        o[mf][nt][r] / li[mf][r];
                }
    }
}

// ---------------------------------------------------------------------------
extern "C" void kernel_launch(void* const* d_in, const int* in_sizes, int n_in,
                              void* d_out, int out_size, void* d_ws, size_t ws_size,
                              hipStream_t stream) {
    int xi = 0, wi[3] = {1, 2, 3};
    {
        int k = 0, found = 0;
        for (int i = 0; i < n_in && i < 8; i++) {
            if (in_sizes[i] == B_ * T_ * DM_) { xi = i; found = 1; }
            else if (in_sizes[i] == H_ * DM_ * D_ && k < 3) wi[k++] = i;
        }
        if (!found || k != 3) { xi = 0; wi[0] = 1; wi[1] = 2; wi[2] = 3; }
    }
    const float* x  = (const float*)d_in[xi];
    const float* Wq = (const float*)d_in[wi[0]];
    const float* Wk = (const float*)d_in[wi[1]];
    const float* Wv = (const float*)d_in[wi[2]];
    float* out = (float*)d_out;

    // bf16 staging scratch lives in d_out (dead before attn writes out):
    //   xb = 8.4M u16 (16.8 MB), Wt = 3.1M u16 (6.3 MB) -> 23.1 of 33.5 MB.
    u16* xb = (u16*)d_out;
    u16* Wt = xb + (size_t)B_ * T_ * DM_;
    // ws: Q + K + Vt bf16 = 50.3 MB (R8-verified to fit).
    const size_t per = (size_t)B_ * H_ * T_ * D_;
    u16* Qc  = (u16*)d_ws;
    u16* Kc  = Qc + per;
    u16* Vtc = Kc + per;

    cvt_x<<<1024, 256, 0, stream>>>(x, xb);
    cvt_w<<<dim3(16, 16, 3), 256, 0, stream>>>(Wq, Wk, Wv, Wt);
    proj_kernel<<<dim3(64, 24), 256, 0, stream>>>(xb, Wt, Qc, Kc, Vtc);
    attn_kernel<<<dim3(8, 16, 4), 256, 0, stream>>>(Qc, Kc, Vtc, out);
}